// Round 12
// baseline (317.932 us; speedup 1.0000x reference)
//
#include <hip/hip_runtime.h>

#define DIM 512
#define B_  64
#define L_  2048

typedef unsigned short u16;
typedef float f32x4 __attribute__((ext_vector_type(4)));
typedef short s16x8 __attribute__((ext_vector_type(8)));
typedef short s16x4 __attribute__((ext_vector_type(4)));

__device__ __forceinline__ u16 f2bf(float f) {
  union { float f; unsigned u; } x{f};
  unsigned r = x.u + 0x7FFFu + ((x.u >> 16) & 1u);
  return (u16)(r >> 16);
}

__device__ __forceinline__ float tanh_fast(float x) {
  float e2 = __expf(2.0f * x);
  return 1.0f - 2.0f / (e2 + 1.0f);
}

// ---------- prep: q = query @ Wq^T + bq ; Wr -> bf16 transposed [t][o][32k] ----------
__global__ __launch_bounds__(256) void prep_kernel(
    const float* __restrict__ query, const float* __restrict__ Wq,
    const float* __restrict__ bq, const float* __restrict__ Wr,
    float* __restrict__ q_out, u16* __restrict__ Wrbt) {
  const int blk = blockIdx.x;
  const int tid = threadIdx.x;
  if (blk < 64) {
    __shared__ float qs[DIM];
    for (int i = tid; i < DIM; i += 256) qs[i] = query[blk * DIM + i];
    __syncthreads();
    for (int o = tid; o < DIM; o += 256) {
      const float* w = Wq + o * DIM;
      float acc = 0.f;
      for (int k = 0; k < DIM; k += 4) {
        f32x4 a = *(const f32x4*)&qs[k];
        f32x4 b = *(const f32x4*)&w[k];
        acc += a.x * b.x + a.y * b.y + a.z * b.z + a.w * b.w;
      }
      q_out[blk * DIM + o] = acc + bq[o];
    }
  } else {
    const int c = blk - 64;
    const int flat = c * 4096 + tid * 16;
    const int o = flat >> 9, k0 = flat & 511;
    const int t = k0 >> 5, kk = k0 & 31;
    u16* dst = Wrbt + t * 16384 + o * 32 + kk;
#pragma unroll
    for (int i = 0; i < 4; ++i) {
      f32x4 a = *(const f32x4*)&Wr[flat + i * 4];
      s16x4 o4;
      o4.x = (short)f2bf(a.x); o4.y = (short)f2bf(a.y);
      o4.z = (short)f2bf(a.z); o4.w = (short)f2bf(a.w);
      *(s16x4*)&dst[i * 4] = o4;
    }
  }
}

// ---------- fused GEMM, block = 128o x 128l, repacked 512B-contiguous e-stores ----------
// grid 4096: og (4, fastest: og-siblings co-resident -> L3 serves shared ref slice),
// b (64), lt (16). 8 waves = 2 wo x 4 wl; wave = 64o x 32l, acc[4][2] (R9-proven).
// B: ref staged per k-chunk to LDS (f32->bf16, dbuf, 1 barrier/t, pitch 40u16).
// A: per-t 1KB loads from L2-hot Wrbt. Epilogue: tanh partials -> u_lds -> upart;
// e repacked through dead B-LDS in 4 phases -> each store instr = 2 rows x 512 B.
__global__ __launch_bounds__(512, 4) void gemm_fused(
    const float* __restrict__ ref, const u16* __restrict__ Wrbt,
    const float* __restrict__ q, const float* __restrict__ br,
    const float* __restrict__ v, float* __restrict__ e_out,
    float* __restrict__ upart) {
  __shared__ u16 Bs[2][128 * 40];   // 20,480 B; repack alias uses 16,896 B
  __shared__ float u_lds[2][128];

  const int bidx = blockIdx.x;
  const int og = bidx & 3, b = (bidx >> 2) & 63, lt = bidx >> 8;

  const int tid = threadIdx.x, lane = tid & 63, w = tid >> 6;
  const int wo = w >> 2, wl = w & 3;
  const int rr = lane & 15, kg = lane >> 4;

  // ---- prologue: stage B chunk t=0 (128 rows x 32 k) ----
  {
    f32x4 sr[2];
#pragma unroll
    for (int p = 0; p < 2; ++p) {
      const int g = p * 512 + tid, row = g >> 3, c8 = g & 7;
      sr[p] = __builtin_nontemporal_load(
          (const f32x4*)&ref[((size_t)(lt * 128 + row) * 64 + b) * 512 + c8 * 4]);
    }
#pragma unroll
    for (int p = 0; p < 2; ++p) {
      const int g = p * 512 + tid, row = g >> 3, c8 = g & 7;
      s16x4 o4;
      o4.x = (short)f2bf(sr[p].x); o4.y = (short)f2bf(sr[p].y);
      o4.z = (short)f2bf(sr[p].z); o4.w = (short)f2bf(sr[p].w);
      *(s16x4*)&Bs[0][row * 40 + c8 * 4] = o4;
    }
  }
  __syncthreads();

  const u16* ap = Wrbt + (og * 128 + wo * 64 + rr) * 32 + kg * 8;

  f32x4 acc[4][2];
#pragma unroll
  for (int fm = 0; fm < 4; ++fm)
#pragma unroll
    for (int fn = 0; fn < 2; ++fn) acc[fm][fn] = (f32x4){0.f, 0.f, 0.f, 0.f};

  for (int t = 0; t < 16; ++t) {
    f32x4 sr[2];
    if (t < 15) {  // issue next B chunk loads early
#pragma unroll
      for (int p = 0; p < 2; ++p) {
        const int g = p * 512 + tid, row = g >> 3, c8 = g & 7;
        sr[p] = __builtin_nontemporal_load(
            (const f32x4*)&ref[((size_t)(lt * 128 + row) * 64 + b) * 512 + (t + 1) * 32 + c8 * 4]);
      }
    }
    s16x8 af[4];
#pragma unroll
    for (int fm = 0; fm < 4; ++fm)
      af[fm] = *(const s16x8*)(ap + t * 16384 + fm * 512);
    s16x8 bf[2];
#pragma unroll
    for (int fn = 0; fn < 2; ++fn) {
      const int row = wl * 32 + fn * 16 + rr;
      bf[fn] = *(const s16x8*)&Bs[t & 1][row * 40 + kg * 8];
    }
#pragma unroll
    for (int fm = 0; fm < 4; ++fm)
#pragma unroll
      for (int fn = 0; fn < 2; ++fn)
        acc[fm][fn] = __builtin_amdgcn_mfma_f32_16x16x32_bf16(bf[fn], af[fm], acc[fm][fn], 0, 0, 0);
    if (t < 15) {
#pragma unroll
      for (int p = 0; p < 2; ++p) {
        const int g = p * 512 + tid, row = g >> 3, c8 = g & 7;
        s16x4 o4;
        o4.x = (short)f2bf(sr[p].x); o4.y = (short)f2bf(sr[p].y);
        o4.z = (short)f2bf(sr[p].z); o4.w = (short)f2bf(sr[p].w);
        *(s16x4*)&Bs[(t + 1) & 1][row * 40 + c8 * 4] = o4;
      }
    }
    __syncthreads();
  }

  // ---- tanh / logits partials (register-only) ----
  float bb[4];
  f32x4 usA[2];
#pragma unroll
  for (int fn = 0; fn < 2; ++fn) usA[fn] = (f32x4){0.f, 0.f, 0.f, 0.f};
#pragma unroll
  for (int fm = 0; fm < 4; ++fm) {
    const int o = og * 128 + wo * 64 + fm * 16 + rr;
    bb[fm] = br[o];
    const float qv = q[b * DIM + o] + bb[fm];
    const float vv = v[o];
#pragma unroll
    for (int fn = 0; fn < 2; ++fn) {
      f32x4 a = acc[fm][fn];
      f32x4 th;
      th.x = tanh_fast(a.x + qv);
      th.y = tanh_fast(a.y + qv);
      th.z = tanh_fast(a.z + qv);
      th.w = tanh_fast(a.w + qv);
      usA[fn] += vv * th;
    }
  }
#pragma unroll
  for (int fn = 0; fn < 2; ++fn) {
    f32x4 us = usA[fn];
#pragma unroll
    for (int msk = 1; msk <= 8; msk <<= 1) {  // reduce over rr (o dim)
      us.x += __shfl_xor(us.x, msk);
      us.y += __shfl_xor(us.y, msk);
      us.z += __shfl_xor(us.z, msk);
      us.w += __shfl_xor(us.w, msk);
    }
    if (rr == 0)
      *(f32x4*)&u_lds[wo][wl * 32 + fn * 16 + kg * 4] = us;
  }

  // ---- e-store via repack: 4 phases, store instr = 2 rows x 512 B contiguous ----
  float* Ebuf = (float*)&Bs[0][0];  // 32 x 132 f32 = 16,896 B (B-LDS dead)
#pragma unroll
  for (int ph = 0; ph < 4; ++ph) {
    if (wo == (ph >> 1)) {
      const int fmb = (ph & 1) * 2;
#pragma unroll
      for (int f2 = 0; f2 < 2; ++f2) {
        const int fm = fmb + f2;
        const int op = f2 * 16 + rr;
#pragma unroll
        for (int fn = 0; fn < 2; ++fn) {
          const int l = wl * 32 + fn * 16 + kg * 4;
          f32x4 ev = acc[fm][fn] + bb[fm];
          *(f32x4*)&Ebuf[op * 132 + l] = ev;
        }
      }
    }
    __syncthreads();
#pragma unroll
    for (int i = 0; i < 2; ++i) {
      const int flat = (w * 2 + i) * 256 + lane * 4;  // 0..4095
      const int op = flat >> 7, lcol = flat & 127;
      f32x4 ev = *(const f32x4*)&Ebuf[op * 132 + lcol];
      __builtin_nontemporal_store(
          ev, (f32x4*)&e_out[((size_t)(b * DIM + og * 128 + ph * 32 + op)) * L_ + lt * 128 + lcol]);
    }
    __syncthreads();
  }

  if (tid < 128)
    upart[(size_t)(og * 64 + b) * L_ + lt * 128 + tid] = u_lds[0][tid] + u_lds[1][tid];
}

// ---------- reduce 4 og partials -> logits ----------
__global__ __launch_bounds__(256) void ured_kernel(
    const float* __restrict__ up, float* __restrict__ out) {
  const int idx = blockIdx.x * 256 + threadIdx.x;
  out[idx] = up[idx] + up[idx + 131072] + up[idx + 262144] + up[idx + 393216];
}

extern "C" void kernel_launch(void* const* d_in, const int* in_sizes, int n_in,
                              void* d_out, int out_size, void* d_ws, size_t ws_size,
                              hipStream_t stream) {
  const float* query = (const float*)d_in[0];
  const float* ref   = (const float*)d_in[1];
  const float* Wq    = (const float*)d_in[2];
  const float* bq    = (const float*)d_in[3];
  const float* Wr    = (const float*)d_in[4];
  const float* br    = (const float*)d_in[5];
  const float* v     = (const float*)d_in[6];

  float* e_out  = (float*)d_out;
  float* logits = e_out + (size_t)B_ * DIM * L_;  // 67108864

  char* ws = (char*)d_ws;
  u16*   Wrbt  = (u16*)ws;                   // 512 KB [16][512][32]
  float* q     = (float*)(ws + 524288);      // 128 KB
  float* upart = (float*)(ws + 655360);      // 2 MB [4][64][2048]

  prep_kernel<<<128, 256, 0, stream>>>(query, Wq, bq, Wr, q, Wrbt);
  gemm_fused<<<4096, 512, 0, stream>>>(ref, Wrbt, q, br, v, e_out, upart);
  ured_kernel<<<512, 256, 0, stream>>>(upart, logits);
}